// Round 11
// baseline (310.714 us; speedup 1.0000x reference)
//
#include <hip/hip_runtime.h>
#include <math.h>

#define N_NODES 50000
#define N_EDGES 800000
#define DIN 256
#define DHID 128
#define DOUT 64
// Padded CSR row stride. In-degree ~ Poisson(16); P(deg > 64) ~ 1e-19 -> safe.
#define CSTRIDE 64
#define ZROW N_NODES            // sentinel row (kept zero)
#define HBLOCKS 128             // one hist block per CU (2 ranges); best makespan
#define HCHUNK (N_EDGES / HBLOCKS)     // 6250
#define HWORDS (N_NODES / 4)           // 12500
#define SLICE ((size_t)(N_NODES + 1) * 16)
#define NGROUPS (N_NODES / 4)          // 12500
#define P2BLOCKS 196                   // hpre blocks (12500/64 word-cols)

// ---------------- fat setup kernel: sentinel-fill csr, 2 histograms, weight folds ----
#define SB_SENT 3125
#define SB_HS (SB_SENT + HBLOCKS)       // 3253
#define SB_HD (SB_HS + HBLOCKS)         // 3381
#define SB_TOT (SB_HD + 66)             // 3447

__global__ void k_setup(const int* __restrict__ src, const int* __restrict__ dst,
                        unsigned int* __restrict__ pS, unsigned int* __restrict__ pD,
                        unsigned int* __restrict__ csr32,
                        const float* __restrict__ W1, const float* __restrict__ b1,
                        const float* __restrict__ W3,
                        float* __restrict__ W13, float* __restrict__ bb,
                        float* __restrict__ Y0, float* __restrict__ Y1) {
    __shared__ unsigned int h[HWORDS];
    int bx = blockIdx.x, t = threadIdx.x;
    if (bx < SB_SENT) {
        // pre-fill every csr slot with the sentinel (k_mid's fill overwrites [0,deg))
        unsigned int v = (unsigned int)ZROW | ((unsigned int)ZROW << 16);
        uint2 o; o.x = v; o.y = v;
        ((uint2*)csr32)[bx * 256 + t] = o;
        return;
    }
    if (bx < SB_HD) {
        // byte-packed LDS-privatized histogram (4 bins per u32); per-block
        // per-node counts <= total degree (<=64) << 255 -> no byte carry.
        // 128 chunks x 2 ranges = 256 hist blocks = exactly 1/CU.
        const int* idx = (bx < SB_HS) ? src : dst;
        unsigned int* outp = (bx < SB_HS) ? pS : pD;
        int hb = bx - ((bx < SB_HS) ? SB_SENT : SB_HS);
        for (int w = t; w < HWORDS; w += 256) h[w] = 0u;
        __syncthreads();
        int base = hb * HCHUNK;
        for (int i = t; i < HCHUNK; i += 256) {
            int s = idx[base + i];
            atomicAdd(&h[s >> 2], 1u << ((s & 3) << 3));
        }
        __syncthreads();
        outp += (size_t)hb * HWORDS;
        for (int w = t; w < HWORDS; w += 256) outp[w] = h[w];
        return;
    }
    int vb = bx - SB_HD;                 // 0..65
    if (vb == 65) {
        if (t < 64) {                    // zero the sentinel row in Y0 (all 4 slices)
            int qq = t >> 4, c2 = t & 15;
            Y0[(size_t)qq * SLICE + ((size_t)ZROW << 4) + c2] = 0.f;
        } else if (t < 128) {            // and in Y1
            int t2 = t - 64;
            int qq = t2 >> 4, c2 = t2 & 15;
            Y1[(size_t)qq * SLICE + ((size_t)ZROW << 4) + c2] = 0.f;
        }
        return;
    }
    if (vb == 64) {
        if (t < DOUT) {
            float s = 0.f;
            for (int k = 0; k < DHID; ++k) s += b1[k] * W3[k * DOUT + t];
            bb[t] = s;
        }
        return;
    }
    int idx2 = vb * 256 + t;             // 16384 outputs of W13 = W1@W3
    int i = idx2 >> 6, j = idx2 & 63;
    float s = 0.f;
    for (int k = 0; k < DHID; ++k) s += W1[i * DHID + k] * W3[k * DOUT + j];
    W13[idx2] = s;
}

// ---------------- hpre: partial-sum + prefix + norms + group max-degree -------------
// thread = (col, sub): col = t>>2 owns packed word wid, sub = t&3 scans 32 of
// the 128 hist blocks. pD values register-cached (full unroll -> static indexing
// -> VGPRs) so the prefix loop re-issues no global reads. Packed byte sums never
// carry (per-node totals <= 64). ns/nd/cc in ORIGINAL numbering; mG[wid] =
// pad8(max in-degree of the 4 nodes in word wid), clamped to 64.
__global__ void k_hpre(const unsigned int* __restrict__ pS,
                       const unsigned int* __restrict__ pD,
                       unsigned int* __restrict__ prefix,
                       float* __restrict__ ns, float* __restrict__ nd,
                       float* __restrict__ cc, int* __restrict__ mG) {
    __shared__ unsigned int sdw[64][4];
    __shared__ unsigned int sow[64][4];
    int t = threadIdx.x;
    int col = t >> 2, sub = t & 3;
    int wid = blockIdx.x * 64 + col;
    bool act = wid < HWORDS;
    unsigned int vals[32];
    unsigned int ps = 0, pd = 0;
    int b0 = sub << 5;
    if (act) {
#pragma unroll
        for (int k = 0; k < 32; ++k) {
            ps += pS[(size_t)(b0 + k) * HWORDS + wid];
            unsigned int w = pD[(size_t)(b0 + k) * HWORDS + wid];
            vals[k] = w;
            pd += w;
        }
    }
    sdw[col][sub] = pd;
    sow[col][sub] = ps;
    __syncthreads();
    if (act) {
        unsigned int base = 0;
        for (int k = 0; k < sub; ++k) base += sdw[col][k];
        unsigned int run = base;
#pragma unroll
        for (int k = 0; k < 32; ++k) {
            prefix[(size_t)(b0 + k) * HWORDS + wid] = run;
            run += vals[k];
        }
        if (sub == 0) {
            unsigned int totd = sdw[col][0] + sdw[col][1] + sdw[col][2] + sdw[col][3];
            unsigned int toto = sow[col][0] + sow[col][1] + sow[col][2] + sow[col][3];
            unsigned int di[4] = {totd & 0xffu, (totd >> 8) & 0xffu,
                                  (totd >> 16) & 0xffu, totd >> 24};
            unsigned int dov[4] = {toto & 0xffu, (toto >> 8) & 0xffu,
                                   (toto >> 16) & 0xffu, toto >> 24};
            float4 vns, vnd, vcc;
            float* pns = &vns.x; float* pnd = &vnd.x; float* pcc = &vcc.x;
            unsigned int mx = 0;
#pragma unroll
            for (int q = 0; q < 4; ++q) {
                if (di[q] > mx) mx = di[q];
                unsigned int a = dov[q] < 1u ? 1u : dov[q];
                unsigned int b = di[q] < 1u ? 1u : di[q];
                float fa = 1.0f / sqrtf((float)a);
                float fb = 1.0f / sqrtf((float)b);
                pns[q] = fa; pnd[q] = fb; pcc[q] = fa * fb;
            }
            *(float4*)(ns + (wid << 2)) = vns;
            *(float4*)(nd + (wid << 2)) = vnd;
            *(float4*)(cc + (wid << 2)) = vcc;
            int m = ((int)mx + 7) & ~7;
            mG[wid] = m > 64 ? 64 : m;
        }
    }
}

// ---------------- k_mid: csr fill || dense GEMM, fused with ALIASED dynamic LDS -----
// Round-10 lesson: the gemm is LDS-READ-throughput-bound (VALUBusy*dur ~= 11 us
// constant across occupancies; dur tracks LDS bytes/FMA). Fix: B operand lives in
// REGISTERS (16 x float4 per thread, full-unroll static indexing; loaded from
// L2-hot 64 KB W13) -> inner loop reads ONLY A from LDS: 1 ds_read_b128 per
// 16 FMA = 819 MB total LDS traffic (was 1.6-2.5 GB). 512 thr, 128x64 tile,
// acc 4x4. Both branches alias one extern __shared__ 50 KB buffer.
#define MB_FILL 128
#define MB_GEMM 391                    // ceil(50000 / 128)
#define MB_TOT (MB_FILL + MB_GEMM)     // 519
#define MID_LDS (HWORDS * 4)           // 50000 B (>= gemm's 8.5 KB)

__global__ void k_mid(const int* __restrict__ src, const int* __restrict__ dst,
                      const unsigned int* __restrict__ prefix,
                      unsigned short* __restrict__ csr,
                      const float* __restrict__ X, const float* __restrict__ W13,
                      const float* __restrict__ ns, float* __restrict__ Y) {
    extern __shared__ char smem[];
    int bx = blockIdx.x, t = threadIdx.x;
    if (bx < MB_FILL) {
        // csr fill (original numbering) using LDS running offsets only
        unsigned int* h = (unsigned int*)smem;
        const unsigned int* prow = prefix + (size_t)bx * HWORDS;
        for (int w = t; w < HWORDS; w += 512) h[w] = prow[w];
        __syncthreads();
        int base = bx * HCHUNK;
        for (int i = t; i < HCHUNK; i += 512) {
            int s = src[base + i], d = dst[base + i];
            int sh = (d & 3) << 3;
            unsigned int old = atomicAdd(&h[d >> 2], 1u << sh);
            int slot = (int)((old >> sh) & 0xffu);
            csr[((size_t)d << 6) + slot] = (unsigned short)s;
        }
        return;
    }
    // dense GEMM: Y[row] = ns[row] * (X @ W13), 128x64 tile, 512 threads, acc 4x4.
    // A staged transposed in LDS [16][132]; B held in registers per k0-tile.
    float* As = (float*)smem;              // 16 x 132 floats = 8.45 KB
    int gb = bx - MB_FILL;
    int row0 = gb * 128;
    int tx = t & 15, ty = t >> 4;          // ty 0..31 (4 rows each), tx 0..15 (4 cols)
    float acc[4][4];
#pragma unroll
    for (int i = 0; i < 4; ++i)
#pragma unroll
        for (int j = 0; j < 4; ++j) acc[i][j] = 0.f;

    int lr = t >> 2;                       // 0..127 (staging row)
    int lk = (t & 3) << 2;                 // 0,4,8,12
    int arow = row0 + lr;
    if (arow > N_NODES - 1) arow = N_NODES - 1;   // clamp: garbage rows never stored
    const float* wp = W13 + (tx << 2);     // this thread's 4-col B slice

    for (int k0 = 0; k0 < DIN; k0 += 16) {
        // stage A tile transposed: 128 rows x 16 k
        float4 a = *(const float4*)(X + (size_t)arow * DIN + k0 + lk);
        As[(lk + 0) * 132 + lr] = a.x; As[(lk + 1) * 132 + lr] = a.y;
        As[(lk + 2) * 132 + lr] = a.z; As[(lk + 3) * 132 + lr] = a.w;
        // B column-slice for this k0-tile -> 16 float4 registers (L2-hot W13)
        float4 breg[16];
#pragma unroll
        for (int kr = 0; kr < 16; ++kr)
            breg[kr] = *(const float4*)(wp + (size_t)(k0 + kr) * DOUT);
        __syncthreads();
#pragma unroll
        for (int k = 0; k < 16; ++k) {
            float4 av = *(const float4*)(As + k * 132 + (ty << 2));
            float ar[4] = {av.x, av.y, av.z, av.w};
            float br[4] = {breg[k].x, breg[k].y, breg[k].z, breg[k].w};
#pragma unroll
            for (int i = 0; i < 4; ++i)
#pragma unroll
                for (int j = 0; j < 4; ++j) acc[i][j] += ar[i] * br[j];
        }
        __syncthreads();
    }
    int qq = tx >> 2;
    int co = (tx & 3) << 2;
#pragma unroll
    for (int i = 0; i < 4; ++i) {
        int row = row0 + (ty << 2) + i;
        if (row < N_NODES) {
            float nsr = ns[row];
            float4 o;
            o.x = acc[i][0] * nsr; o.y = acc[i][1] * nsr;
            o.z = acc[i][2] * nsr; o.w = acc[i][3] * nsr;
            *(float4*)(Y + (size_t)qq * SLICE + ((size_t)row << 4) + co) = o;
        }
    }
}

// ---------------- sliced pull SpMM: 4 nodes x 4 edge-slots x float4 ------------------
// Round-0-proven structure; loop bound m = mG[g] (pad8 group max in-degree);
// slots [deg, m) hold the sentinel row (zero, L1-hot single line -> near-free).
// LDS rows stored TRANSPOSED [entry*4 + node]: hot-loop ds_read_u16 addresses
// hit 8 distinct banks -> conflict-free. q = (bx&7)>>1 pins each column slice
// to one XCD pair (3.2 MB slice << 8 MB L2 pair) for cross-pass L2 residency.
// At fp32 the pass time is bounded by vector-memory address processing
// (16 lanes/edge invariant across layouts -- rounds 3/4 proved insensitivity).
// MODE 0: y = cc*acc + ns*bb[col]; MODE 1: y = cc*acc;
// MODE 2: out[node] = nd*acc + b3[col]  (row-major [N][64]).

template <int MODE>
__launch_bounds__(256, 8)
__global__ void k_spmm(const float* __restrict__ xs, float* __restrict__ ys,
                       const unsigned short* __restrict__ csr,
                       const int* __restrict__ mG,
                       const float* __restrict__ cc, const float* __restrict__ ns,
                       const float* __restrict__ nd,
                       const float* __restrict__ bb, const float* __restrict__ b3) {
    __shared__ unsigned short rows[4][256];     // [wave][entry*4 + node] = 2 KB
    int wid  = threadIdx.x >> 6;
    int lane = threadIdx.x & 63;
    int q    = (blockIdx.x & 7) >> 1;
    int half = blockIdx.x & 1;
    int g    = (blockIdx.x >> 3) * 8 + wid * 2 + half;   // 4-node group id
    if (g >= NGROUPS) return;
    int node0 = g << 2;

    // stage 4 csr rows (4 x 128 B) into LDS, transposed: lane (nn,sl) loads
    // entries 4sl..4sl+3 of node nn and writes them at [(4sl+k)*4 + nn].
    int nn = lane >> 4, sl = lane & 15;
    const uint2* crow = (const uint2*)(csr + ((size_t)(node0 + nn) << 6)) + sl;
    uint2 rv = *crow;
    unsigned short* bp = &rows[wid][(sl << 4) + nn];
    bp[0]  = (unsigned short)(rv.x & 0xffffu);
    bp[4]  = (unsigned short)(rv.x >> 16);
    bp[8]  = (unsigned short)(rv.y & 0xffffu);
    bp[12] = (unsigned short)(rv.y >> 16);

    int m = __builtin_amdgcn_readfirstlane(mG[g]);       // pad8 group max, <= 64

    int n = lane >> 4, e = (lane >> 2) & 3, c4 = lane & 3;
    const unsigned short* rd = &rows[wid][(e << 2) + n];   // entry (e+4T) at rd[16T]
    const float* xq = xs + (size_t)q * SLICE + (c4 << 2);

    float ax = 0.f, ay = 0.f, az = 0.f, aw = 0.f;
#define LDV(T) const float4 v##T = *(const float4*)(xq + ((size_t)rd[16 * (T)] << 4))
#define ACCV(T) ax += v##T.x; ay += v##T.y; az += v##T.z; aw += v##T.w
    if (m <= 8) {
        LDV(0); LDV(1);
        ACCV(0); ACCV(1);
    } else if (m <= 16) {
        LDV(0); LDV(1); LDV(2); LDV(3);
        ACCV(0); ACCV(1); ACCV(2); ACCV(3);
    } else if (m <= 24) {
        LDV(0); LDV(1); LDV(2); LDV(3); LDV(4); LDV(5);
        ACCV(0); ACCV(1); ACCV(2); ACCV(3); ACCV(4); ACCV(5);
    } else if (m <= 32) {
        LDV(0); LDV(1); LDV(2); LDV(3); LDV(4); LDV(5); LDV(6); LDV(7);
        ACCV(0); ACCV(1); ACCV(2); ACCV(3); ACCV(4); ACCV(5); ACCV(6); ACCV(7);
    } else {
        for (int j2 = 0; j2 < m; j2 += 8) {
            int o = j2 << 2;
            const float4 a = *(const float4*)(xq + ((size_t)rd[o] << 4));
            const float4 b = *(const float4*)(xq + ((size_t)rd[o + 16] << 4));
            ax += a.x; ay += a.y; az += a.z; aw += a.w;
            ax += b.x; ay += b.y; az += b.z; aw += b.w;
        }
    }
#undef LDV
#undef ACCV
    // reduce over edge-slots e (lane bits 2..3)
    ax += __shfl_xor(ax, 4);  ay += __shfl_xor(ay, 4);
    az += __shfl_xor(az, 4);  aw += __shfl_xor(aw, 4);
    ax += __shfl_xor(ax, 8);  ay += __shfl_xor(ay, 8);
    az += __shfl_xor(az, 8);  aw += __shfl_xor(aw, 8);

    int nodeL = node0 + n;
    int colq  = (q << 4) + (c4 << 2);
    float4 r;
    if (MODE == 0) {
        float cv = cc[nodeL], nv = ns[nodeL];
        float4 bv = *(const float4*)(bb + colq);
        r.x = cv * ax + nv * bv.x; r.y = cv * ay + nv * bv.y;
        r.z = cv * az + nv * bv.z; r.w = cv * aw + nv * bv.w;
    } else if (MODE == 1) {
        float cv = cc[nodeL];
        r.x = cv * ax; r.y = cv * ay; r.z = cv * az; r.w = cv * aw;
    } else {
        float dv = nd[nodeL];
        float4 bv = *(const float4*)(b3 + colq);
        r.x = dv * ax + bv.x; r.y = dv * ay + bv.y;
        r.z = dv * az + bv.z; r.w = dv * aw + bv.w;
    }
    if (e == 0) {
        if (MODE == 2) {
            *(float4*)(ys + ((size_t)nodeL << 6) + colq) = r;
        } else {
            *(float4*)(ys + (size_t)q * SLICE + ((size_t)nodeL << 4) + (c4 << 2)) = r;
        }
    }
}

// ---------------- launcher ----------------

extern "C" void kernel_launch(void* const* d_in, const int* in_sizes, int n_in,
                              void* d_out, int out_size, void* d_ws, size_t ws_size,
                              hipStream_t stream) {
    const float* X   = (const float*)d_in[0];
    const int*   src = (const int*)d_in[1];
    const int*   dst = (const int*)d_in[2];
    const float* W1  = (const float*)d_in[3];
    const float* b1  = (const float*)d_in[4];
    const float* W3  = (const float*)d_in[5];
    const float* b3  = (const float*)d_in[6];
    float* out = (float*)d_out;

    char* ws = (char*)d_ws;
    size_t off = 0;
    auto alloc = [&](size_t bytes) -> void* {
        void* p = ws + off;
        off = (off + bytes + 255) & ~(size_t)255;
        return p;
    };
    unsigned int*   pS   = (unsigned int*)alloc((size_t)HBLOCKS * HWORDS * 4);
    unsigned int*   pD   = (unsigned int*)alloc((size_t)HBLOCKS * HWORDS * 4);
    unsigned int*   pref = (unsigned int*)alloc((size_t)HBLOCKS * HWORDS * 4);
    float*          Y0   = (float*)alloc(SLICE * 4 * 4);
    float*          Y1   = (float*)alloc(SLICE * 4 * 4);
    unsigned short* csr  = (unsigned short*)alloc((size_t)N_NODES * CSTRIDE * 2);
    float*          ns   = (float*)alloc((size_t)N_NODES * 4);
    float*          nd   = (float*)alloc((size_t)N_NODES * 4);
    float*          cc   = (float*)alloc((size_t)N_NODES * 4);
    int*            mG   = (int*)alloc((size_t)NGROUPS * 4);
    float*          W13  = (float*)alloc((size_t)DIN * DOUT * 4);
    float*          bb   = (float*)alloc(DOUT * 4);

    const int sblk = 1563 * 8;   // 12504 blocks -> 12500 groups x 4 slices

    k_setup<<<SB_TOT, 256, 0, stream>>>(src, dst, pS, pD, (unsigned int*)csr,
                                        W1, b1, W3, W13, bb, Y0, Y1);
    k_hpre<<<P2BLOCKS, 256, 0, stream>>>(pS, pD, pref, ns, nd, cc, mG);
    k_mid<<<MB_TOT, 512, MID_LDS, stream>>>(src, dst, pref, csr, X, W13, ns, Y0);

    // 6 propagation passes; bias bb injected in pass 1, b3 in pass 6
    k_spmm<0><<<sblk, 256, 0, stream>>>(Y0, Y1, csr, mG, cc, ns, nd, bb, b3);
    k_spmm<1><<<sblk, 256, 0, stream>>>(Y1, Y0, csr, mG, cc, ns, nd, bb, b3);
    k_spmm<1><<<sblk, 256, 0, stream>>>(Y0, Y1, csr, mG, cc, ns, nd, bb, b3);
    k_spmm<1><<<sblk, 256, 0, stream>>>(Y1, Y0, csr, mG, cc, ns, nd, bb, b3);
    k_spmm<1><<<sblk, 256, 0, stream>>>(Y0, Y1, csr, mG, cc, ns, nd, bb, b3);
    k_spmm<2><<<sblk, 256, 0, stream>>>(Y1, out, csr, mG, cc, ns, nd, bb, b3);
}

// Round 13
// 286.163 us; speedup vs baseline: 1.0858x; 1.0858x over previous
//
#include <hip/hip_runtime.h>
#include <math.h>

#define N_NODES 50000
#define N_EDGES 800000
#define DIN 256
#define DHID 128
#define DOUT 64
// Padded CSR row stride. In-degree ~ Poisson(16); P(deg > 64) ~ 1e-19 -> safe.
#define CSTRIDE 64
#define ZROW N_NODES            // sentinel row (kept zero)
#define HBLOCKS 128             // one hist block per CU (2 ranges); best makespan
#define HCHUNK (N_EDGES / HBLOCKS)     // 6250
#define HWORDS (N_NODES / 4)           // 12500
#define SLICE ((size_t)(N_NODES + 1) * 16)
#define NGROUPS (N_NODES / 4)          // 12500
#define P2BLOCKS 196                   // hpre blocks (12500/64 word-cols)

// ---------------- fat setup kernel: sentinel-fill csr, 2 histograms, weight folds ----
#define SB_SENT 3125
#define SB_HS (SB_SENT + HBLOCKS)       // 3253
#define SB_HD (SB_HS + HBLOCKS)         // 3381
#define SB_TOT (SB_HD + 66)             // 3447

__global__ void k_setup(const int* __restrict__ src, const int* __restrict__ dst,
                        unsigned int* __restrict__ pS, unsigned int* __restrict__ pD,
                        unsigned int* __restrict__ csr32,
                        const float* __restrict__ W1, const float* __restrict__ b1,
                        const float* __restrict__ W3,
                        float* __restrict__ W13, float* __restrict__ bb,
                        float* __restrict__ Y0, float* __restrict__ Y1) {
    __shared__ unsigned int h[HWORDS];
    int bx = blockIdx.x, t = threadIdx.x;
    if (bx < SB_SENT) {
        // pre-fill every csr slot with the sentinel (k_mid's fill overwrites [0,deg))
        unsigned int v = (unsigned int)ZROW | ((unsigned int)ZROW << 16);
        uint2 o; o.x = v; o.y = v;
        ((uint2*)csr32)[bx * 256 + t] = o;
        return;
    }
    if (bx < SB_HD) {
        // byte-packed LDS-privatized histogram (4 bins per u32); per-block
        // per-node counts <= total degree (<=64) << 255 -> no byte carry.
        // 128 chunks x 2 ranges = 256 hist blocks = exactly 1/CU.
        const int* idx = (bx < SB_HS) ? src : dst;
        unsigned int* outp = (bx < SB_HS) ? pS : pD;
        int hb = bx - ((bx < SB_HS) ? SB_SENT : SB_HS);
        for (int w = t; w < HWORDS; w += 256) h[w] = 0u;
        __syncthreads();
        int base = hb * HCHUNK;
        for (int i = t; i < HCHUNK; i += 256) {
            int s = idx[base + i];
            atomicAdd(&h[s >> 2], 1u << ((s & 3) << 3));
        }
        __syncthreads();
        outp += (size_t)hb * HWORDS;
        for (int w = t; w < HWORDS; w += 256) outp[w] = h[w];
        return;
    }
    int vb = bx - SB_HD;                 // 0..65
    if (vb == 65) {
        if (t < 64) {                    // zero the sentinel row in Y0 (all 4 slices)
            int qq = t >> 4, c2 = t & 15;
            Y0[(size_t)qq * SLICE + ((size_t)ZROW << 4) + c2] = 0.f;
        } else if (t < 128) {            // and in Y1
            int t2 = t - 64;
            int qq = t2 >> 4, c2 = t2 & 15;
            Y1[(size_t)qq * SLICE + ((size_t)ZROW << 4) + c2] = 0.f;
        }
        return;
    }
    if (vb == 64) {
        if (t < DOUT) {
            float s = 0.f;
            for (int k = 0; k < DHID; ++k) s += b1[k] * W3[k * DOUT + t];
            bb[t] = s;
        }
        return;
    }
    int idx2 = vb * 256 + t;             // 16384 outputs of W13 = W1@W3
    int i = idx2 >> 6, j = idx2 & 63;
    float s = 0.f;
    for (int k = 0; k < DHID; ++k) s += W1[i * DHID + k] * W3[k * DOUT + j];
    W13[idx2] = s;
}

// ---------------- hpre: partial-sum + prefix + norms + group max-degree -------------
// thread = (col, sub): col = t>>2 owns packed word wid, sub = t&3 scans 32 of
// the 128 hist blocks. pD values register-cached (full unroll -> static indexing
// -> VGPRs) so the prefix loop re-issues no global reads. Packed byte sums never
// carry (per-node totals <= 64). ns/nd/cc in ORIGINAL numbering; mG[wid] =
// pad8(max in-degree of the 4 nodes in word wid), clamped to 64.
__global__ void k_hpre(const unsigned int* __restrict__ pS,
                       const unsigned int* __restrict__ pD,
                       unsigned int* __restrict__ prefix,
                       float* __restrict__ ns, float* __restrict__ nd,
                       float* __restrict__ cc, int* __restrict__ mG) {
    __shared__ unsigned int sdw[64][4];
    __shared__ unsigned int sow[64][4];
    int t = threadIdx.x;
    int col = t >> 2, sub = t & 3;
    int wid = blockIdx.x * 64 + col;
    bool act = wid < HWORDS;
    unsigned int vals[32];
    unsigned int ps = 0, pd = 0;
    int b0 = sub << 5;
    if (act) {
#pragma unroll
        for (int k = 0; k < 32; ++k) {
            ps += pS[(size_t)(b0 + k) * HWORDS + wid];
            unsigned int w = pD[(size_t)(b0 + k) * HWORDS + wid];
            vals[k] = w;
            pd += w;
        }
    }
    sdw[col][sub] = pd;
    sow[col][sub] = ps;
    __syncthreads();
    if (act) {
        unsigned int base = 0;
        for (int k = 0; k < sub; ++k) base += sdw[col][k];
        unsigned int run = base;
#pragma unroll
        for (int k = 0; k < 32; ++k) {
            prefix[(size_t)(b0 + k) * HWORDS + wid] = run;
            run += vals[k];
        }
        if (sub == 0) {
            unsigned int totd = sdw[col][0] + sdw[col][1] + sdw[col][2] + sdw[col][3];
            unsigned int toto = sow[col][0] + sow[col][1] + sow[col][2] + sow[col][3];
            unsigned int di[4] = {totd & 0xffu, (totd >> 8) & 0xffu,
                                  (totd >> 16) & 0xffu, totd >> 24};
            unsigned int dov[4] = {toto & 0xffu, (toto >> 8) & 0xffu,
                                   (toto >> 16) & 0xffu, toto >> 24};
            float4 vns, vnd, vcc;
            float* pns = &vns.x; float* pnd = &vnd.x; float* pcc = &vcc.x;
            unsigned int mx = 0;
#pragma unroll
            for (int q = 0; q < 4; ++q) {
                if (di[q] > mx) mx = di[q];
                unsigned int a = dov[q] < 1u ? 1u : dov[q];
                unsigned int b = di[q] < 1u ? 1u : di[q];
                float fa = 1.0f / sqrtf((float)a);
                float fb = 1.0f / sqrtf((float)b);
                pns[q] = fa; pnd[q] = fb; pcc[q] = fa * fb;
            }
            *(float4*)(ns + (wid << 2)) = vns;
            *(float4*)(nd + (wid << 2)) = vnd;
            *(float4*)(cc + (wid << 2)) = vcc;
            int m = ((int)mx + 7) & ~7;
            mG[wid] = m > 64 ? 64 : m;
        }
    }
}

// ---------------- k_mid: csr fill || dense GEMM, fused with ALIASED dynamic LDS -----
// Round-11 lesson: B must stay in LDS (broadcast); per-thread global B loads are
// issue/latency-poison. LDS-byte model (4 data points): dur tracks bytes/FMA =
// 4(1/r + 1/c) at fixed block coverage. This round: r=8 c=4 per thread at 256
// threads -> tile stays 128x64 -> 391 gemm blocks (full coverage) at 1.5 B/FMA
// (round 9 was 2.0). Fill branch = proven 256-thread round-7 body. Both branches
// alias one extern __shared__ 50 KB buffer (round-6 summed-static-LDS trap).
#define MB_FILL 128
#define MB_GEMM 391                    // ceil(50000 / 128)
#define MB_TOT (MB_FILL + MB_GEMM)     // 519
#define MID_LDS (HWORDS * 4)           // 50000 B (>= gemm's 12.5 KB)

__global__ void k_mid(const int* __restrict__ src, const int* __restrict__ dst,
                      const unsigned int* __restrict__ prefix,
                      unsigned short* __restrict__ csr,
                      const float* __restrict__ X, const float* __restrict__ W13,
                      const float* __restrict__ ns, float* __restrict__ Y) {
    extern __shared__ char smem[];
    int bx = blockIdx.x, t = threadIdx.x;
    if (bx < MB_FILL) {
        // csr fill (original numbering) using LDS running offsets only
        unsigned int* h = (unsigned int*)smem;
        const unsigned int* prow = prefix + (size_t)bx * HWORDS;
        for (int w = t; w < HWORDS; w += 256) h[w] = prow[w];
        __syncthreads();
        int base = bx * HCHUNK;
        for (int i = t; i < HCHUNK; i += 256) {
            int s = src[base + i], d = dst[base + i];
            int sh = (d & 3) << 3;
            unsigned int old = atomicAdd(&h[d >> 2], 1u << sh);
            int slot = (int)((old >> sh) & 0xffu);
            csr[((size_t)d << 6) + slot] = (unsigned short)s;
        }
        return;
    }
    // dense GEMM: Y[row] = ns[row] * (X @ W13), 128x64 tile, 256 threads, acc 8x4.
    float* As = (float*)smem;              // [16][132] = 8.45 KB
    float* Bs = (float*)smem + 16 * 132;   // [16][64]  = 4 KB
    int gb = bx - MB_FILL;
    int row0 = gb * 128;
    int tx = t & 15, ty = t >> 4;          // ty 0..15 (8 rows each), tx 0..15 (4 cols)
    float acc[8][4];
#pragma unroll
    for (int i = 0; i < 8; ++i)
#pragma unroll
        for (int j = 0; j < 4; ++j) acc[i][j] = 0.f;

    int lr = t >> 1;                       // 0..127 (staging row)
    int lk = (t & 1) << 3;                 // 0 or 8
    int arow = row0 + lr;
    if (arow > N_NODES - 1) arow = N_NODES - 1;   // clamp: garbage rows never stored

    for (int k0 = 0; k0 < DIN; k0 += 16) {
        // stage A tile transposed: 128 rows x 16 k (each thread 2 float4)
        float4 a0 = *(const float4*)(X + (size_t)arow * DIN + k0 + lk);
        float4 a1 = *(const float4*)(X + (size_t)arow * DIN + k0 + lk + 4);
        As[(lk + 0) * 132 + lr] = a0.x; As[(lk + 1) * 132 + lr] = a0.y;
        As[(lk + 2) * 132 + lr] = a0.z; As[(lk + 3) * 132 + lr] = a0.w;
        As[(lk + 4) * 132 + lr] = a1.x; As[(lk + 5) * 132 + lr] = a1.y;
        As[(lk + 6) * 132 + lr] = a1.z; As[(lk + 7) * 132 + lr] = a1.w;
        // stage B tile: 16 k x 64 cols (each thread 1 float4)
        {
            int kr = t >> 4;               // 0..15
            int kc = (t & 15) << 2;        // 0..60
            float4 b = *(const float4*)(W13 + (size_t)(k0 + kr) * DOUT + kc);
            *(float4*)(Bs + kr * 64 + kc) = b;
        }
        __syncthreads();
#pragma unroll
        for (int k = 0; k < 16; ++k) {
            float4 av0 = *(const float4*)(As + k * 132 + (ty << 3));
            float4 av1 = *(const float4*)(As + k * 132 + (ty << 3) + 4);
            float4 bv  = *(const float4*)(Bs + k * 64 + (tx << 2));
            float ar[8] = {av0.x, av0.y, av0.z, av0.w, av1.x, av1.y, av1.z, av1.w};
            float br[4] = {bv.x, bv.y, bv.z, bv.w};
#pragma unroll
            for (int i = 0; i < 8; ++i)
#pragma unroll
                for (int j = 0; j < 4; ++j) acc[i][j] += ar[i] * br[j];
        }
        __syncthreads();
    }
    int qq = tx >> 2;
    int co = (tx & 3) << 2;
#pragma unroll
    for (int i = 0; i < 8; ++i) {
        int row = row0 + (ty << 3) + i;
        if (row < N_NODES) {
            float nsr = ns[row];
            float4 o;
            o.x = acc[i][0] * nsr; o.y = acc[i][1] * nsr;
            o.z = acc[i][2] * nsr; o.w = acc[i][3] * nsr;
            *(float4*)(Y + (size_t)qq * SLICE + ((size_t)row << 4) + co) = o;
        }
    }
}

// ---------------- sliced pull SpMM: 4 nodes x 4 edge-slots x float4 ------------------
// Round-0-proven structure; loop bound m = mG[g] (pad8 group max in-degree);
// slots [deg, m) hold the sentinel row (zero, L1-hot single line -> near-free).
// LDS rows stored TRANSPOSED [entry*4 + node]: hot-loop ds_read_u16 addresses
// hit 8 distinct banks -> conflict-free. q = (bx&7)>>1 pins each column slice
// to one XCD pair (3.2 MB slice << 8 MB L2 pair) for cross-pass L2 residency.
// At fp32 the pass time is bounded by vector-memory address processing
// (16 lanes/edge invariant across layouts -- rounds 3/4 proved insensitivity).
// MODE 0: y = cc*acc + ns*bb[col]; MODE 1: y = cc*acc;
// MODE 2: out[node] = nd*acc + b3[col]  (row-major [N][64]).

template <int MODE>
__launch_bounds__(256, 8)
__global__ void k_spmm(const float* __restrict__ xs, float* __restrict__ ys,
                       const unsigned short* __restrict__ csr,
                       const int* __restrict__ mG,
                       const float* __restrict__ cc, const float* __restrict__ ns,
                       const float* __restrict__ nd,
                       const float* __restrict__ bb, const float* __restrict__ b3) {
    __shared__ unsigned short rows[4][256];     // [wave][entry*4 + node] = 2 KB
    int wid  = threadIdx.x >> 6;
    int lane = threadIdx.x & 63;
    int q    = (blockIdx.x & 7) >> 1;
    int half = blockIdx.x & 1;
    int g    = (blockIdx.x >> 3) * 8 + wid * 2 + half;   // 4-node group id
    if (g >= NGROUPS) return;
    int node0 = g << 2;

    // stage 4 csr rows (4 x 128 B) into LDS, transposed: lane (nn,sl) loads
    // entries 4sl..4sl+3 of node nn and writes them at [(4sl+k)*4 + nn].
    int nn = lane >> 4, sl = lane & 15;
    const uint2* crow = (const uint2*)(csr + ((size_t)(node0 + nn) << 6)) + sl;
    uint2 rv = *crow;
    unsigned short* bp = &rows[wid][(sl << 4) + nn];
    bp[0]  = (unsigned short)(rv.x & 0xffffu);
    bp[4]  = (unsigned short)(rv.x >> 16);
    bp[8]  = (unsigned short)(rv.y & 0xffffu);
    bp[12] = (unsigned short)(rv.y >> 16);

    int m = __builtin_amdgcn_readfirstlane(mG[g]);       // pad8 group max, <= 64

    int n = lane >> 4, e = (lane >> 2) & 3, c4 = lane & 3;
    const unsigned short* rd = &rows[wid][(e << 2) + n];   // entry (e+4T) at rd[16T]
    const float* xq = xs + (size_t)q * SLICE + (c4 << 2);

    float ax = 0.f, ay = 0.f, az = 0.f, aw = 0.f;
#define LDV(T) const float4 v##T = *(const float4*)(xq + ((size_t)rd[16 * (T)] << 4))
#define ACCV(T) ax += v##T.x; ay += v##T.y; az += v##T.z; aw += v##T.w
    if (m <= 8) {
        LDV(0); LDV(1);
        ACCV(0); ACCV(1);
    } else if (m <= 16) {
        LDV(0); LDV(1); LDV(2); LDV(3);
        ACCV(0); ACCV(1); ACCV(2); ACCV(3);
    } else if (m <= 24) {
        LDV(0); LDV(1); LDV(2); LDV(3); LDV(4); LDV(5);
        ACCV(0); ACCV(1); ACCV(2); ACCV(3); ACCV(4); ACCV(5);
    } else if (m <= 32) {
        LDV(0); LDV(1); LDV(2); LDV(3); LDV(4); LDV(5); LDV(6); LDV(7);
        ACCV(0); ACCV(1); ACCV(2); ACCV(3); ACCV(4); ACCV(5); ACCV(6); ACCV(7);
    } else {
        for (int j2 = 0; j2 < m; j2 += 8) {
            int o = j2 << 2;
            const float4 a = *(const float4*)(xq + ((size_t)rd[o] << 4));
            const float4 b = *(const float4*)(xq + ((size_t)rd[o + 16] << 4));
            ax += a.x; ay += a.y; az += a.z; aw += a.w;
            ax += b.x; ay += b.y; az += b.z; aw += b.w;
        }
    }
#undef LDV
#undef ACCV
    // reduce over edge-slots e (lane bits 2..3)
    ax += __shfl_xor(ax, 4);  ay += __shfl_xor(ay, 4);
    az += __shfl_xor(az, 4);  aw += __shfl_xor(aw, 4);
    ax += __shfl_xor(ax, 8);  ay += __shfl_xor(ay, 8);
    az += __shfl_xor(az, 8);  aw += __shfl_xor(aw, 8);

    int nodeL = node0 + n;
    int colq  = (q << 4) + (c4 << 2);
    float4 r;
    if (MODE == 0) {
        float cv = cc[nodeL], nv = ns[nodeL];
        float4 bv = *(const float4*)(bb + colq);
        r.x = cv * ax + nv * bv.x; r.y = cv * ay + nv * bv.y;
        r.z = cv * az + nv * bv.z; r.w = cv * aw + nv * bv.w;
    } else if (MODE == 1) {
        float cv = cc[nodeL];
        r.x = cv * ax; r.y = cv * ay; r.z = cv * az; r.w = cv * aw;
    } else {
        float dv = nd[nodeL];
        float4 bv = *(const float4*)(b3 + colq);
        r.x = dv * ax + bv.x; r.y = dv * ay + bv.y;
        r.z = dv * az + bv.z; r.w = dv * aw + bv.w;
    }
    if (e == 0) {
        if (MODE == 2) {
            *(float4*)(ys + ((size_t)nodeL << 6) + colq) = r;
        } else {
            *(float4*)(ys + (size_t)q * SLICE + ((size_t)nodeL << 4) + (c4 << 2)) = r;
        }
    }
}

// ---------------- launcher ----------------

extern "C" void kernel_launch(void* const* d_in, const int* in_sizes, int n_in,
                              void* d_out, int out_size, void* d_ws, size_t ws_size,
                              hipStream_t stream) {
    const float* X   = (const float*)d_in[0];
    const int*   src = (const int*)d_in[1];
    const int*   dst = (const int*)d_in[2];
    const float* W1  = (const float*)d_in[3];
    const float* b1  = (const float*)d_in[4];
    const float* W3  = (const float*)d_in[5];
    const float* b3  = (const float*)d_in[6];
    float* out = (float*)d_out;

    char* ws = (char*)d_ws;
    size_t off = 0;
    auto alloc = [&](size_t bytes) -> void* {
        void* p = ws + off;
        off = (off + bytes + 255) & ~(size_t)255;
        return p;
    };
    unsigned int*   pS   = (unsigned int*)alloc((size_t)HBLOCKS * HWORDS * 4);
    unsigned int*   pD   = (unsigned int*)alloc((size_t)HBLOCKS * HWORDS * 4);
    unsigned int*   pref = (unsigned int*)alloc((size_t)HBLOCKS * HWORDS * 4);
    float*          Y0   = (float*)alloc(SLICE * 4 * 4);
    float*          Y1   = (float*)alloc(SLICE * 4 * 4);
    unsigned short* csr  = (unsigned short*)alloc((size_t)N_NODES * CSTRIDE * 2);
    float*          ns   = (float*)alloc((size_t)N_NODES * 4);
    float*          nd   = (float*)alloc((size_t)N_NODES * 4);
    float*          cc   = (float*)alloc((size_t)N_NODES * 4);
    int*            mG   = (int*)alloc((size_t)NGROUPS * 4);
    float*          W13  = (float*)alloc((size_t)DIN * DOUT * 4);
    float*          bb   = (float*)alloc(DOUT * 4);

    const int sblk = 1563 * 8;   // 12504 blocks -> 12500 groups x 4 slices

    k_setup<<<SB_TOT, 256, 0, stream>>>(src, dst, pS, pD, (unsigned int*)csr,
                                        W1, b1, W3, W13, bb, Y0, Y1);
    k_hpre<<<P2BLOCKS, 256, 0, stream>>>(pS, pD, pref, ns, nd, cc, mG);
    k_mid<<<MB_TOT, 256, MID_LDS, stream>>>(src, dst, pref, csr, X, W13, ns, Y0);

    // 6 propagation passes; bias bb injected in pass 1, b3 in pass 6
    k_spmm<0><<<sblk, 256, 0, stream>>>(Y0, Y1, csr, mG, cc, ns, nd, bb, b3);
    k_spmm<1><<<sblk, 256, 0, stream>>>(Y1, Y0, csr, mG, cc, ns, nd, bb, b3);
    k_spmm<1><<<sblk, 256, 0, stream>>>(Y0, Y1, csr, mG, cc, ns, nd, bb, b3);
    k_spmm<1><<<sblk, 256, 0, stream>>>(Y1, Y0, csr, mG, cc, ns, nd, bb, b3);
    k_spmm<1><<<sblk, 256, 0, stream>>>(Y0, Y1, csr, mG, cc, ns, nd, bb, b3);
    k_spmm<2><<<sblk, 256, 0, stream>>>(Y1, out, csr, mG, cc, ns, nd, bb, b3);
}